// Round 2
// baseline (541.246 us; speedup 1.0000x reference)
//
#include <hip/hip_runtime.h>
#include <math.h>

// (T,B,C,H,W) = (9,8,256,56,56), fp32.
// Fully fused: scores -> softmax(t) -> attend, one dispatch.
// Math note (validated round 1, absmax 7.8e-3): score_center and bias are
// constant along the softmax axis t -> shift-invariant -> dropped entirely.
#define TT 9
#define BN 8
#define CC 256
#define HW 3136
#define PIX 32             // pixels per block tile (3136 = 32*98)
#define CHUNKS (HW / PIX)  // 98
#define CPART 16           // channel partitions (512 thr = 16 cpart x 32 pix)
#define CPC (CC / CPART)   // 16 channels per partition
#define CENTER_T 4

__global__ __launch_bounds__(512) void fused_tfma_kernel(
    const float* __restrict__ seq, const float* __restrict__ w,
    const float* __restrict__ gamma, float* __restrict__ out) {
  int blk = blockIdx.x;
  int chunk = blk % CHUNKS;
  int b = blk / CHUNKS;
  int hw0 = chunk * PIX;
  int tid = threadIdx.x;
  int pix = tid & (PIX - 1);
  int cpart = tid >> 5;  // 0..15
  int c0 = cpart * CPC;

  __shared__ float w_o[CC];
  __shared__ float red[TT * CPART * PIX];  // 4608 f = 18 KB
  __shared__ float sc[TT * PIX];           // scores -> attn, 288 f

  if (tid < CC) w_o[tid] = w[CC + tid];
  __syncthreads();

  // base points at seq[0, b, 0, hw0+pix]
  const float* base = seq + ((size_t)b * CC) * HW + hw0 + pix;

  // ---- Phase A: partial scores over this thread's 16 channels ----
  #pragma unroll
  for (int t = 0; t < TT; ++t) {
    const float* bt = base + (size_t)t * BN * CC * HW;
    float a = 0.f;
    #pragma unroll
    for (int i = 0; i < CPC; ++i)
      a = fmaf(bt[(size_t)(c0 + i) * HW], w_o[c0 + i], a);
    red[(t * CPART + cpart) * PIX + pix] = a;
  }
  __syncthreads();

  // ---- Reduce 16 partials per (t,pix), then per-pixel softmax over t ----
  if (tid < TT * PIX) {
    int t = tid >> 5, p = tid & (PIX - 1);
    float s = 0.f;
    #pragma unroll
    for (int cp = 0; cp < CPART; ++cp) s += red[(t * CPART + cp) * PIX + p];
    sc[t * PIX + p] = s;
  }
  __syncthreads();
  if (tid < PIX) {
    float v[TT], m = -1e30f;
    #pragma unroll
    for (int t = 0; t < TT; ++t) {
      v[t] = sc[t * PIX + tid];
      m = fmaxf(m, v[t]);
    }
    float s = 0.f;
    #pragma unroll
    for (int t = 0; t < TT; ++t) { v[t] = __expf(v[t] - m); s += v[t]; }
    float inv = 1.f / s;
    // column `tid` owned exclusively by this thread -> safe in-place
    #pragma unroll
    for (int t = 0; t < TT; ++t) sc[t * PIX + tid] = v[t] * inv;
  }
  __syncthreads();

  // ---- Phase B: attend (re-read tile; L2/L3-warm) + center + write ----
  float at[TT];
  #pragma unroll
  for (int t = 0; t < TT; ++t) at[t] = sc[t * PIX + pix];

  float oacc[CPC], cen[CPC];
  #pragma unroll
  for (int i = 0; i < CPC; ++i) oacc[i] = 0.f;
  #pragma unroll
  for (int t = 0; t < TT; ++t) {
    const float* bt = base + (size_t)t * BN * CC * HW;
    float a = at[t];
    #pragma unroll
    for (int i = 0; i < CPC; ++i) {
      float v = bt[(size_t)(c0 + i) * HW];
      oacc[i] = fmaf(a, v, oacc[i]);
      if (t == CENTER_T) cen[i] = v;
    }
  }
  float g = gamma[0];
  float* ob = out + ((size_t)b * CC) * HW + hw0 + pix;
  #pragma unroll
  for (int i = 0; i < CPC; ++i)
    ob[(size_t)(c0 + i) * HW] = fmaf(g, oacc[i], cen[i]);
}

extern "C" void kernel_launch(void* const* d_in, const int* in_sizes, int n_in,
                              void* d_out, int out_size, void* d_ws, size_t ws_size,
                              hipStream_t stream) {
  const float* seq = (const float*)d_in[0];
  const float* w = (const float*)d_in[1];
  // d_in[2] (bias) unused: softmax shift-invariant.
  const float* gamma = (const float*)d_in[3];
  float* out = (float*)d_out;

  fused_tfma_kernel<<<BN * CHUNKS, 512, 0, stream>>>(seq, w, gamma, out);
}

// Round 3
// 355.133 us; speedup vs baseline: 1.5241x; 1.5241x over previous
//
#include <hip/hip_runtime.h>
#include <math.h>

// (T,B,C,H,W) = (9,8,256,56,56), fp32.
// Two kernels, float4-vectorized over hw:
//  K1: scores[t,b,hw] = sum_c seq*w_other (center/bias dropped: softmax
//      shift-invariance, validated rounds 1-2, absmax 7.8e-3)
//  K2: in-register softmax over t + attend + residual. seq re-read hits
//      L2/L3 (round-2 FETCH_SIZE proved 231MB seq is cache-resident).
#define TT 9
#define BN 8
#define CC 256
#define HW 3136
#define HW4 (HW / 4)       // 784 float4 groups
#define BHW (BN * HW)
#define CENTER_T 4
#define GPT 16             // float4-groups per block tile (= 64 pixels)
#define CHUNKS (HW4 / GPT) // 49

// K1: grid = (t*BN+b) * CHUNKS; 256 thr = 16 groups x 16 cparts (16 ch each).
__global__ __launch_bounds__(256) void scores_kernel(
    const float* __restrict__ seq, const float* __restrict__ w,
    float* __restrict__ scores) {
  int blk = blockIdx.x;
  int chunk = blk % CHUNKS;
  int tb = blk / CHUNKS;  // t*BN + b
  int tid = threadIdx.x;
  int g = tid & 15;
  int cpart = tid >> 4;
  int c0 = cpart * 16;
  int px = (chunk * GPT + g) * 4;

  __shared__ float w_o[CC];
  __shared__ float4 red[16][16];
  w_o[tid] = w[CC + tid];
  __syncthreads();

  const float4* base = (const float4*)(seq + (size_t)tb * CC * HW + px);
  float4 acc = {0.f, 0.f, 0.f, 0.f};
  #pragma unroll
  for (int i = 0; i < 16; ++i) {
    float4 v = base[(size_t)(c0 + i) * HW4];
    float wc = w_o[c0 + i];
    acc.x = fmaf(v.x, wc, acc.x);
    acc.y = fmaf(v.y, wc, acc.y);
    acc.z = fmaf(v.z, wc, acc.z);
    acc.w = fmaf(v.w, wc, acc.w);
  }
  red[cpart][g] = acc;
  __syncthreads();
  if (tid < 16) {
    float4 s = {0.f, 0.f, 0.f, 0.f};
    #pragma unroll
    for (int cp = 0; cp < 16; ++cp) {
      float4 r = red[cp][tid];
      s.x += r.x; s.y += r.y; s.z += r.z; s.w += r.w;
    }
    *(float4*)(scores + (size_t)tb * HW + (chunk * GPT + tid) * 4) = s;
  }
}

// K2: grid = b(8) x cg(4) x chunk(49); 256 thr = 16 groups x 16 csubs (4 ch).
// Softmax recomputed per thread in registers (cheap; scores tiny).
__global__ __launch_bounds__(256) void attend_kernel(
    const float* __restrict__ seq, const float* __restrict__ scores,
    const float* __restrict__ gamma, float* __restrict__ out) {
  int blk = blockIdx.x;
  int chunk = blk % CHUNKS;
  int rest = blk / CHUNKS;
  int cg = rest & 3;
  int b = rest >> 2;
  int tid = threadIdx.x;
  int g = tid & 15;
  int csub = tid >> 4;
  int c0 = cg * 64 + csub * 4;
  int px = (chunk * GPT + g) * 4;

  // ---- softmax over t for this thread's 4 pixels ----
  float4 att[TT];
  {
    const float4* sp = (const float4*)(scores + (size_t)b * HW + px);
    float4 m = {-1e30f, -1e30f, -1e30f, -1e30f};
    #pragma unroll
    for (int t = 0; t < TT; ++t) {
      att[t] = sp[(size_t)t * (BHW / 4)];
      m.x = fmaxf(m.x, att[t].x);
      m.y = fmaxf(m.y, att[t].y);
      m.z = fmaxf(m.z, att[t].z);
      m.w = fmaxf(m.w, att[t].w);
    }
    float4 s = {0.f, 0.f, 0.f, 0.f};
    #pragma unroll
    for (int t = 0; t < TT; ++t) {
      att[t].x = __expf(att[t].x - m.x); s.x += att[t].x;
      att[t].y = __expf(att[t].y - m.y); s.y += att[t].y;
      att[t].z = __expf(att[t].z - m.z); s.z += att[t].z;
      att[t].w = __expf(att[t].w - m.w); s.w += att[t].w;
    }
    float4 inv = {1.f / s.x, 1.f / s.y, 1.f / s.z, 1.f / s.w};
    #pragma unroll
    for (int t = 0; t < TT; ++t) {
      att[t].x *= inv.x; att[t].y *= inv.y;
      att[t].z *= inv.z; att[t].w *= inv.w;
    }
  }

  // ---- attend over t, 4 channels x 4 pixels per thread ----
  const float4* base = (const float4*)(seq + ((size_t)b * CC + c0) * HW + px);
  float4 acc[4];
  float4 cen[4];
  #pragma unroll
  for (int i = 0; i < 4; ++i) acc[i] = {0.f, 0.f, 0.f, 0.f};
  #pragma unroll
  for (int t = 0; t < TT; ++t) {
    const float4* bt = base + (size_t)t * BN * CC * HW4;
    float4 a = att[t];
    #pragma unroll
    for (int i = 0; i < 4; ++i) {
      float4 v = bt[(size_t)i * HW4];
      acc[i].x = fmaf(a.x, v.x, acc[i].x);
      acc[i].y = fmaf(a.y, v.y, acc[i].y);
      acc[i].z = fmaf(a.z, v.z, acc[i].z);
      acc[i].w = fmaf(a.w, v.w, acc[i].w);
      if (t == CENTER_T) cen[i] = v;
    }
  }
  float gm = gamma[0];
  float4* ob = (float4*)(out + ((size_t)b * CC + c0) * HW + px);
  #pragma unroll
  for (int i = 0; i < 4; ++i) {
    float4 o;
    o.x = fmaf(gm, acc[i].x, cen[i].x);
    o.y = fmaf(gm, acc[i].y, cen[i].y);
    o.z = fmaf(gm, acc[i].z, cen[i].z);
    o.w = fmaf(gm, acc[i].w, cen[i].w);
    ob[(size_t)i * HW4] = o;
  }
}

extern "C" void kernel_launch(void* const* d_in, const int* in_sizes, int n_in,
                              void* d_out, int out_size, void* d_ws, size_t ws_size,
                              hipStream_t stream) {
  const float* seq = (const float*)d_in[0];
  const float* w = (const float*)d_in[1];
  // d_in[2] (bias) unused: softmax shift-invariant.
  const float* gamma = (const float*)d_in[3];
  float* out = (float*)d_out;
  float* scores = (float*)d_ws;  // T*B*HW*4 = 903168 B

  scores_kernel<<<TT * BN * CHUNKS, 256, 0, stream>>>(seq, w, scores);
  attend_kernel<<<BN * 4 * CHUNKS, 256, 0, stream>>>(seq, scores, gamma, out);
}

// Round 4
// 343.189 us; speedup vs baseline: 1.5771x; 1.0348x over previous
//
#include <hip/hip_runtime.h>
#include <math.h>

// (T,B,C,H,W) = (9,8,256,56,56), fp32.
// Single-pass fused kernel: per (b, 8-pixel chunk) stage the full 9x256x8
// tile (72 KB) into LDS once, then scores -> softmax -> attend from LDS.
// seq is read from HBM exactly ONCE (231 MB) vs two passes before.
// Math note (validated rounds 1-3, absmax 7.8e-3): score_center and bias
// are constant along softmax axis t -> shift-invariant -> dropped.
#define TT 9
#define BN 8
#define CC 256
#define HW 3136
#define P 8               // pixels per block
#define NCHUNK (HW / P)   // 392
#define CENTER_T 4

__global__ __launch_bounds__(256) void fused_stage_kernel(
    const float* __restrict__ seq, const float* __restrict__ w,
    const float* __restrict__ gamma, float* __restrict__ out) {
  // XCD swizzle: blk%8 -> XCD (heuristic); give each XCD one batch image so
  // its L2 merges the 32B row segments of consecutive chunks into full lines.
  int blk = blockIdx.x;
  int b = blk & 7;
  int chunk = blk >> 3;    // 0..391, consecutive on the same XCD
  int px0 = chunk * P;
  int tid = threadIdx.x;

  __shared__ __align__(16) float tile[TT * CC * P];  // 73728 B
  __shared__ float wsh[CC];
  __shared__ float red[TT * P * 4];                  // 288 partials
  __shared__ __align__(16) float sc[TT * P];         // attn weights

  wsh[tid] = w[CC + tid];  // w_other

  // ---- Stage: 4608 float4 = 18 per thread, fully coalesced-ish ----
  {
    const float* sb = seq + px0;
    #pragma unroll
    for (int k = 0; k < 18; ++k) {
      int i = k * 256 + tid;
      int t = i >> 9;          // 512 items (256c x 2 groups) per t
      int r = i & 511;
      int c = r >> 1;
      int g = (r & 1) * 4;
      float4 v = *(const float4*)(sb + (((size_t)t * BN + b) * CC + c) * HW + g);
      *(float4*)(&tile[(t * CC + c) * P + g]) = v;
    }
  }
  __syncthreads();

  // ---- Scores: 288 work items = 72 (t,px) pairs x 4 c-partitions ----
  for (int v = tid; v < 288; v += 256) {
    int pair = v >> 2;       // t*8 + px
    int cp = v & 3;
    int t = pair >> 3;
    int px = pair & 7;
    int c0 = cp * 64;
    float a = 0.f;
    #pragma unroll
    for (int i = 0; i < 64; ++i)
      a = fmaf(tile[(t * CC + c0 + i) * P + px], wsh[c0 + i], a);
    red[pair * 4 + cp] = a;
  }
  __syncthreads();

  // ---- Reduce partials + softmax over t (one thread per pixel) ----
  if (tid < P) {
    float vv[TT];
    float m = -1e30f;
    #pragma unroll
    for (int t = 0; t < TT; ++t) {
      int pr = (t * P + tid) * 4;
      float s = red[pr] + red[pr + 1] + red[pr + 2] + red[pr + 3];
      vv[t] = s;
      m = fmaxf(m, s);
    }
    float s = 0.f;
    #pragma unroll
    for (int t = 0; t < TT; ++t) { vv[t] = __expf(vv[t] - m); s += vv[t]; }
    float inv = 1.f / s;
    #pragma unroll
    for (int t = 0; t < TT; ++t) sc[t * P + tid] = vv[t] * inv;
  }
  __syncthreads();

  // ---- Attend: thread = channel, all 8 pixels; sc reads are broadcasts ----
  {
    int c = tid;
    float4 o0 = {0.f, 0.f, 0.f, 0.f}, o1 = {0.f, 0.f, 0.f, 0.f};
    float4 c0v = {0.f, 0.f, 0.f, 0.f}, c1v = {0.f, 0.f, 0.f, 0.f};
    #pragma unroll
    for (int t = 0; t < TT; ++t) {
      float4 s0 = *(const float4*)(&sc[t * P]);
      float4 s1 = *(const float4*)(&sc[t * P + 4]);
      const float4* tp = (const float4*)(&tile[(t * CC + c) * P]);
      float4 v0 = tp[0], v1 = tp[1];
      o0.x = fmaf(s0.x, v0.x, o0.x);
      o0.y = fmaf(s0.y, v0.y, o0.y);
      o0.z = fmaf(s0.z, v0.z, o0.z);
      o0.w = fmaf(s0.w, v0.w, o0.w);
      o1.x = fmaf(s1.x, v1.x, o1.x);
      o1.y = fmaf(s1.y, v1.y, o1.y);
      o1.z = fmaf(s1.z, v1.z, o1.z);
      o1.w = fmaf(s1.w, v1.w, o1.w);
      if (t == CENTER_T) { c0v = v0; c1v = v1; }
    }
    float gm = gamma[0];
    float4 r0, r1;
    r0.x = fmaf(gm, o0.x, c0v.x);
    r0.y = fmaf(gm, o0.y, c0v.y);
    r0.z = fmaf(gm, o0.z, c0v.z);
    r0.w = fmaf(gm, o0.w, c0v.w);
    r1.x = fmaf(gm, o1.x, c1v.x);
    r1.y = fmaf(gm, o1.y, c1v.y);
    r1.z = fmaf(gm, o1.z, c1v.z);
    r1.w = fmaf(gm, o1.w, c1v.w);
    float* ob = out + ((size_t)b * CC + c) * HW + px0;
    *(float4*)(ob) = r0;
    *(float4*)(ob + 4) = r1;
  }
}

extern "C" void kernel_launch(void* const* d_in, const int* in_sizes, int n_in,
                              void* d_out, int out_size, void* d_ws, size_t ws_size,
                              hipStream_t stream) {
  const float* seq = (const float*)d_in[0];
  const float* w = (const float*)d_in[1];
  // d_in[2] (bias) unused: softmax shift-invariant.
  const float* gamma = (const float*)d_in[3];
  float* out = (float*)d_out;

  fused_stage_kernel<<<BN * NCHUNK, 256, 0, stream>>>(seq, w, gamma, out);
}